// Round 16
// baseline (828.098 us; speedup 1.0000x reference)
//
#include <hip/hip_runtime.h>
#include <hip/hip_bf16.h>
#include <math.h>

#define N_NODES 50000
#define N_EDGES 800000
#define N_GRAPHS 64
#define E2_TOTAL (N_EDGES + N_NODES)
#define NBX ((N_NODES + 63) / 64)       // xw8 blocks
#define NBD ((N_EDGES + 255) / 256)     // deg blocks

typedef unsigned short u16;
typedef __attribute__((ext_vector_type(8))) short s16x8;
typedef __attribute__((ext_vector_type(4))) float f32x4;
typedef __attribute__((ext_vector_type(2))) float f32x2;

__device__ __forceinline__ u16 f2bf(float f) {
    unsigned u = __float_as_uint(f);
    u += 0x7fffu + ((u >> 16) & 1u);   // round-to-nearest-even
    return (u16)(u >> 16);
}
__device__ __forceinline__ void unpack2(unsigned v, float& a, float& b) {
    a = __uint_as_float(v << 16);
    b = __uint_as_float(v & 0xffff0000u);
}
__device__ __forceinline__ f32x2 up2(unsigned v) {
    f32x2 r;
    r.x = __uint_as_float(v << 16);
    r.y = __uint_as_float(v & 0xffff0000u);
    return r;
}
__device__ __forceinline__ unsigned pack2(float a, float b) {
    return (unsigned)f2bf(a) | ((unsigned)f2bf(b) << 16);
}
__device__ __forceinline__ float elu_fast(float u) {
    return u > 0.f ? u : __expf(u) - 1.f;
}

// ---------------------------------------------------------------- prep: xw8 (blocks [0,NBX)) + deg histogram (blocks [NBX, NBX+NBD))

__global__ __launch_bounds__(256) void prep_kernel(
    const float* __restrict__ x, const float* __restrict__ Wl,
    const float* __restrict__ bl, const float* __restrict__ Wr,
    const float* __restrict__ br, u16* __restrict__ Xa, u16* __restrict__ Xb,
    const int* __restrict__ ei, int* __restrict__ deg, int N, int E) {
    int tid = threadIdx.x;
    if (blockIdx.x >= NBX) {
        int e = (blockIdx.x - NBX) * 256 + tid;
        if (e < E) atomicAdd(&deg[ei[E + e]], 1);
        return;
    }
    __shared__ float sWl[8 * 512], sWr[8 * 512];
    __shared__ float sbl[512], sbr[512];
    __shared__ float sx[64][8];
    int nb = blockIdx.x * 64;
    for (int i = tid; i < 8 * 512; i += 256) { sWl[i] = Wl[i]; sWr[i] = Wr[i]; }
    for (int i = tid; i < 512; i += 256) { sbl[i] = bl[i]; sbr[i] = br[i]; }
    for (int i = tid; i < 64 * 8; i += 256) {
        int j = i >> 3, k = i & 7;
        int n = nb + j;
        sx[j][k] = (n < N) ? x[(size_t)n * 8 + k] : 0.f;
    }
    __syncthreads();
    for (int it = 0; it < 64; it++) {
        int i = tid + it * 256;
        int j = i >> 8, c2 = (i & 255) * 2;
        int n = nb + j;
        if (n < N) {
            float l0 = sbl[c2], l1 = sbl[c2 + 1];
            float r0 = sbr[c2], r1 = sbr[c2 + 1];
            #pragma unroll
            for (int k = 0; k < 8; k++) {
                float xv = sx[j][k];
                l0 += xv * sWl[k * 512 + c2];
                l1 += xv * sWl[k * 512 + c2 + 1];
                r0 += xv * sWr[k * 512 + c2];
                r1 += xv * sWr[k * 512 + c2 + 1];
            }
            *reinterpret_cast<unsigned*>(Xa + (size_t)n * 512 + c2) = pack2(l0, l1);
            *reinterpret_cast<unsigned*>(Xb + (size_t)n * 512 + c2) = pack2(r0, r1);
        }
    }
}

// exclusive scan of (deg+1); writes rowptr AND cursor
__global__ __launch_bounds__(1024) void scan_kernel(const int* __restrict__ deg,
                                                    int* __restrict__ rowptr,
                                                    int* __restrict__ cursor, int N) {
    __shared__ int wsum[16];
    __shared__ int carry_s;
    int tid = threadIdx.x, lane = tid & 63, wid = tid >> 6;
    if (tid == 0) carry_s = 0;
    __syncthreads();
    for (int base = 0; base < N; base += 4096) {
        int i0 = base + tid * 4;
        int d0 = (i0 + 0 < N) ? deg[i0 + 0] + 1 : 0;
        int d1 = (i0 + 1 < N) ? deg[i0 + 1] + 1 : 0;
        int d2 = (i0 + 2 < N) ? deg[i0 + 2] + 1 : 0;
        int d3 = (i0 + 3 < N) ? deg[i0 + 3] + 1 : 0;
        int v = d0 + d1 + d2 + d3;
        int x = v;
        #pragma unroll
        for (int off = 1; off < 64; off <<= 1) {
            int t = __shfl_up(x, off);
            if (lane >= off) x += t;
        }
        if (lane == 63) wsum[wid] = x;
        __syncthreads();
        if (wid == 0) {
            int y = (lane < 16) ? wsum[lane] : 0;
            #pragma unroll
            for (int off = 1; off < 16; off <<= 1) {
                int t = __shfl_up(y, off);
                if (lane >= off) y += t;
            }
            if (lane < 16) wsum[lane] = y;
        }
        __syncthreads();
        int woff = (wid > 0) ? wsum[wid - 1] : 0;
        int excl = carry_s + woff + x - v;
        if (i0 + 0 < N) { rowptr[i0 + 0] = excl;                cursor[i0 + 0] = excl; }
        if (i0 + 1 < N) { rowptr[i0 + 1] = excl + d0;           cursor[i0 + 1] = excl + d0; }
        if (i0 + 2 < N) { rowptr[i0 + 2] = excl + d0 + d1;      cursor[i0 + 2] = excl + d0 + d1; }
        if (i0 + 3 < N) { rowptr[i0 + 3] = excl + d0 + d1 + d2; cursor[i0 + 3] = excl + d0 + d1 + d2; }
        __syncthreads();
        if (tid == 1023) carry_s += wsum[15];
        __syncthreads();
    }
    if (threadIdx.x == 0) rowptr[N] = carry_s;
}

// CSR fill (real edges only): meta[pos] = {ea0, ea1, ea2, src}
__global__ __launch_bounds__(256) void fill_kernel(const int* __restrict__ ei,
                                                   const float* __restrict__ eattr,
                                                   int* __restrict__ cursor,
                                                   float4* __restrict__ meta, int E) {
    int e = blockIdx.x * 256 + threadIdx.x;
    if (e >= E) return;
    int src = ei[e], dst = ei[E + e];
    float a0 = eattr[(size_t)e * 3 + 0];
    float a1 = eattr[(size_t)e * 3 + 1];
    float a2 = eattr[(size_t)e * 3 + 2];
    int pos = atomicAdd(&cursor[dst], 1);
    meta[pos] = make_float4(a0, a1, a2, __int_as_float(src));
}

// self-loop fill: one wave per node reduces its real-edge attrs, writes the
// self-loop entry into the LAST slot of the node's CSR range.
__global__ __launch_bounds__(256) void loopfill_kernel(const int* __restrict__ rowptr,
                                                       float4* __restrict__ meta, int N) {
    int n = blockIdx.x * 4 + (threadIdx.x >> 6);
    int lane = threadIdx.x & 63;
    if (n >= N) return;
    int beg = __builtin_amdgcn_readfirstlane(rowptr[n]);
    int e1  = __builtin_amdgcn_readfirstlane(rowptr[n + 1]) - 1;  // self-loop slot
    float a0 = 0.f, a1 = 0.f, a2 = 0.f;
    for (int j = beg + lane; j < e1; j += 64) {
        float4 md = meta[j];
        a0 += md.x; a1 += md.y; a2 += md.z;
    }
    #pragma unroll
    for (int off = 32; off; off >>= 1) {
        a0 += __shfl_xor(a0, off);
        a1 += __shfl_xor(a1, off);
        a2 += __shfl_xor(a2, off);
    }
    if (lane == 0) {
        int cnt = e1 - beg;
        float inv = 1.f / (float)max(cnt, 1);
        meta[e1] = make_float4(a0 * inv, a1 * inv, a2 * inv, __int_as_float(n));
    }
}

// ---------------------------------------------------------------- bucket reduce helper (in-block, 256 thr)

__device__ __forceinline__ float2 reduce_buckets(const double* __restrict__ buck,
                                                 double count) {
    __shared__ float2 res;
    int t = threadIdx.x;
    double s  = buck[t * 2]     + buck[(t + 256) * 2];
    double s2 = buck[t * 2 + 1] + buck[(t + 256) * 2 + 1];
    #pragma unroll
    for (int off = 32; off; off >>= 1) {
        s += __shfl_xor(s, off);
        s2 += __shfl_xor(s2, off);
    }
    __shared__ double a[4], b[4];
    int wid = t >> 6, lane = t & 63;
    if (lane == 0) { a[wid] = s; b[wid] = s2; }
    __syncthreads();
    if (t == 0) {
        double S = a[0] + a[1] + a[2] + a[3];
        double S2 = b[0] + b[1] + b[2] + b[3];
        double mu = S / count;
        double var = S2 / count - mu * mu;
        float sd = (float)sqrt(var > 0.0 ? var : 0.0);
        res.x = (float)mu;
        res.y = 1.f / (sd + 1e-5f);
    }
    __syncthreads();
    return res;
}

// ---------------------------------------------------------------- W -> Wt bf16 transpose (dual via blockIdx.z)

__global__ __launch_bounds__(256) void wt_dual(const float* __restrict__ WL,
                                               const float* __restrict__ WR,
                                               u16* __restrict__ WtL,
                                               u16* __restrict__ WtR, int K, int M) {
    const float* W = blockIdx.z ? WR : WL;
    u16* Wt = blockIdx.z ? WtR : WtL;
    __shared__ u16 t[64][65];
    int kb = blockIdx.x * 64, mb = blockIdx.y * 64;
    int tid = threadIdx.x;
    for (int i = tid; i < 64 * 64; i += 256) {
        int k = i >> 6, m = i & 63;
        t[m][k] = f2bf(W[(size_t)(kb + k) * M + mb + m]);
    }
    __syncthreads();
    for (int i = tid; i < 64 * 64; i += 256) {
        int m = i >> 6, k = i & 63;
        Wt[(size_t)(mb + m) * K + kb + k] = t[m][k];
    }
}

// ---------------------------------------------------------------- MFMA GEMM, L and R fused in one pass
// A-tile staged ONCE with fused LayerNorm + fast-ELU, used against both BtL
// and BtR (af fragments reused). XOR-swizzled LDS (write and read).

__global__ __launch_bounds__(256) void gemm_LR(const u16* __restrict__ A,
                                               const u16* __restrict__ BtL,
                                               const u16* __restrict__ BtR,
                                               const float* __restrict__ biasL,
                                               const float* __restrict__ biasR,
                                               u16* __restrict__ YL,
                                               u16* __restrict__ YR,
                                               const double* __restrict__ buck,
                                               double count,
                                               const float* __restrict__ lnw,
                                               const float* __restrict__ lnb,
                                               int N, int K, int M) {
    constexpr int BM = 128, BK = 64;
    __shared__ u16 As[BM][BK];
    __shared__ u16 BsL[BM][BK];
    __shared__ u16 BsR[BM][BK];
    __shared__ float sLw[512], sLb[512];
    float2 lp = reduce_buckets(buck, count);
    float muf = lp.x, rs = lp.y;
    int tid = threadIdx.x;
    for (int i = tid; i < K; i += 256) { sLw[i] = lnw[i] * rs; sLb[i] = lnb[i]; }
    int wid = tid >> 6, lane = tid & 63;
    int wm = (wid >> 1) * 64, wn = (wid & 1) * 64;
    int bm = blockIdx.x * BM, bn = blockIdx.y * BM;
    int l15 = lane & 15, l4 = lane >> 4;
    f32x4 accL[4][4] = {};
    f32x4 accR[4][4] = {};
    int sr = tid >> 3;            // 0..31
    int cbw = tid & 7;            // col-block 0..7
    int sc = cbw * 8;
    __syncthreads();

    for (int k0 = 0; k0 < K; k0 += BK) {
        #pragma unroll
        for (int p = 0; p < 4; p++) {
            int r = p * 32 + sr;
            int swc = ((cbw ^ (r & 7)) * 8);
            int grow = bm + r;
            uint4 av = make_uint4(0, 0, 0, 0);
            if (grow < N) {
                av = *reinterpret_cast<const uint4*>(A + (size_t)grow * K + k0 + sc);
                float f[8];
                unpack2(av.x, f[0], f[1]); unpack2(av.y, f[2], f[3]);
                unpack2(av.z, f[4], f[5]); unpack2(av.w, f[6], f[7]);
                #pragma unroll
                for (int q = 0; q < 8; q++) {
                    int c = k0 + sc + q;
                    f[q] = elu_fast((f[q] - muf) * sLw[c] + sLb[c]);
                }
                av = make_uint4(pack2(f[0], f[1]), pack2(f[2], f[3]),
                                pack2(f[4], f[5]), pack2(f[6], f[7]));
            }
            *reinterpret_cast<uint4*>(&As[r][swc]) = av;
            *reinterpret_cast<uint4*>(&BsL[r][swc]) =
                *reinterpret_cast<const uint4*>(BtL + (size_t)(bn + r) * K + k0 + sc);
            *reinterpret_cast<uint4*>(&BsR[r][swc]) =
                *reinterpret_cast<const uint4*>(BtR + (size_t)(bn + r) * K + k0 + sc);
        }
        __syncthreads();
        #pragma unroll
        for (int kk = 0; kk < 2; kk++) {
            int CB = kk * 4 + l4;     // col-block 0..7
            s16x8 af[4], bfL[4], bfR[4];
            #pragma unroll
            for (int i = 0; i < 4; i++) {
                int Ra = wm + i * 16 + l15;
                int Rb = wn + i * 16 + l15;
                int sa = (CB ^ (Ra & 7)) * 8;
                int sb = (CB ^ (Rb & 7)) * 8;
                af[i]  = *reinterpret_cast<const s16x8*>(&As[Ra][sa]);
                bfL[i] = *reinterpret_cast<const s16x8*>(&BsL[Rb][sb]);
                bfR[i] = *reinterpret_cast<const s16x8*>(&BsR[Rb][sb]);
            }
            #pragma unroll
            for (int i = 0; i < 4; i++)
                #pragma unroll
                for (int j = 0; j < 4; j++) {
                    accL[i][j] = __builtin_amdgcn_mfma_f32_16x16x32_bf16(
                        af[i], bfL[j], accL[i][j], 0, 0, 0);
                    accR[i][j] = __builtin_amdgcn_mfma_f32_16x16x32_bf16(
                        af[i], bfR[j], accR[i][j], 0, 0, 0);
                }
        }
        __syncthreads();
    }
    #pragma unroll
    for (int i = 0; i < 4; i++) {
        #pragma unroll
        for (int j = 0; j < 4; j++) {
            int col = bn + wn + j * 16 + l15;
            float bvL = biasL[col];
            float bvR = biasR[col];
            #pragma unroll
            for (int r = 0; r < 4; r++) {
                int row = bm + wm + i * 16 + l4 * 4 + r;
                if (row < N) {
                    YL[(size_t)row * M + col] = f2bf(accL[i][j][r] + bvL);
                    YR[(size_t)row * M + col] = f2bf(accR[i][j][r] + bvR);
                }
            }
        }
    }
}

// ---------------------------------------------------------------- wave-per-node GATv2
// SPLIT waves per node. Scalar (SGPR) row bases, packed-f32 channel math,
// 2 edges/iter with 2-ahead prefetch, defer-max softmax, LN-stat buckets.

template <int HC, int SPLIT, bool F32OUT>
__global__ __launch_bounds__(256) void attn_wave(
    const int* __restrict__ rowptr, const float4* __restrict__ meta,
    const u16* __restrict__ XLbf, const u16* __restrict__ XRbf,
    const float* __restrict__ We, const float* __restrict__ att,
    const float* __restrict__ bo, float* __restrict__ outf,
    u16* __restrict__ outb, double* __restrict__ sbuck, int N) {
    constexpr int CW  = HC / SPLIT;   // channels per wave
    constexpr int CPL = CW / 64;      // 8, 4 or 2
    constexpr int P2  = CPL / 2;      // float2 pairs per lane
    constexpr int GS  = 128 / CPL;    // lanes per head group (16/32/64)
    constexpr int SHB = (HC == 512) ? 10 : (HC == 256) ? 9 : 8;  // log2(row bytes)
    int gw = blockIdx.x * 4 + (threadIdx.x >> 6);
    int lane = threadIdx.x & 63;
    int n = gw / SPLIT;
    int sub = gw - n * SPLIT;
    if (n >= N) return;
    int cb = sub * CW + lane * CPL;

    f32x2 xr2[P2], we0v[P2], we1v[P2], we2v[P2], sav[P2], accv[P2];
    #pragma unroll
    for (int i = 0; i < P2; i++) {
        we0v[i] = *reinterpret_cast<const f32x2*>(&We[cb + 2 * i]);
        we1v[i] = *reinterpret_cast<const f32x2*>(&We[HC + cb + 2 * i]);
        we2v[i] = *reinterpret_cast<const f32x2*>(&We[2 * HC + cb + 2 * i]);
        sav[i]  = *reinterpret_cast<const f32x2*>(&att[cb + 2 * i]);
        accv[i] = f32x2{0.f, 0.f};
    }
    auto ldrow = [&](const u16* base, int idx) -> uint4 {
        const u16* p = (const u16*)((const char*)base +
                       ((size_t)((unsigned)idx << SHB))) + cb;
        if constexpr (CPL == 8) {
            return *reinterpret_cast<const uint4*>(p);
        } else if constexpr (CPL == 4) {
            uint2 r = *reinterpret_cast<const uint2*>(p);
            return make_uint4(r.x, r.y, 0, 0);
        } else {
            return make_uint4(*reinterpret_cast<const unsigned*>(p), 0, 0, 0);
        }
    };
    auto toF2 = [&](uint4 r, f32x2* v) {
        v[0] = up2(r.x);
        if constexpr (CPL >= 4) v[1] = up2(r.y);
        if constexpr (CPL == 8) { v[2] = up2(r.z); v[3] = up2(r.w); }
    };
    {
        uint4 r = ldrow(XRbf, n);
        toF2(r, xr2);
    }

    int beg = __builtin_amdgcn_readfirstlane(rowptr[n]);
    int end = __builtin_amdgcn_readfirstlane(rowptr[n + 1]);
    int e1 = end - 1;
    float m = -INFINITY, l = 0.f;

    float4 mdA = meta[beg];
    float4 mdB = meta[min(beg + 1, e1)];
    int sA = __builtin_amdgcn_readfirstlane(__float_as_int(mdA.w));
    int sB = __builtin_amdgcn_readfirstlane(__float_as_int(mdB.w));
    uint4 rA = ldrow(XLbf, sA), rB = ldrow(XLbf, sB);

    for (int j = beg; j < end; j += 2) {
        float4 mdA_n = meta[min(j + 2, e1)];
        float4 mdB_n = meta[min(j + 3, e1)];
        int sAn = __builtin_amdgcn_readfirstlane(__float_as_int(mdA_n.w));
        int sBn = __builtin_amdgcn_readfirstlane(__float_as_int(mdB_n.w));
        uint4 rA_n = ldrow(XLbf, sAn), rB_n = ldrow(XLbf, sBn);

        f32x2 xl0v[P2], xl1v[P2];
        toF2(rA, xl0v);
        toF2(rB, xl1v);
        f32x2 pv0 = {0.f, 0.f}, pv1 = {0.f, 0.f};
        f32x2 ax0 = {mdA.x, mdA.x}, ay0 = {mdA.y, mdA.y}, az0 = {mdA.z, mdA.z};
        f32x2 ax1 = {mdB.x, mdB.x}, ay1 = {mdB.y, mdB.y}, az1 = {mdB.z, mdB.z};
        #pragma unroll
        for (int i = 0; i < P2; i++) {
            f32x2 u0 = __builtin_elementwise_fma(ax0, we0v[i],
                       __builtin_elementwise_fma(ay0, we1v[i],
                       __builtin_elementwise_fma(az0, we2v[i], xl0v[i] + xr2[i])));
            f32x2 u1 = __builtin_elementwise_fma(ax1, we0v[i],
                       __builtin_elementwise_fma(ay1, we1v[i],
                       __builtin_elementwise_fma(az1, we2v[i], xl1v[i] + xr2[i])));
            f32x2 lr0 = __builtin_elementwise_max(u0, u0 * 0.2f);
            f32x2 lr1 = __builtin_elementwise_max(u1, u1 * 0.2f);
            pv0 = __builtin_elementwise_fma(lr0, sav[i], pv0);
            pv1 = __builtin_elementwise_fma(lr1, sav[i], pv1);
        }
        float p0 = pv0.x + pv0.y;
        float p1 = pv1.x + pv1.y;
        #pragma unroll
        for (int off = GS / 2; off >= 1; off >>= 1) {
            p0 += __shfl_xor(p0, off);
            p1 += __shfl_xor(p1, off);
        }
        if (j + 1 > e1) p1 = -INFINITY;   // odd tail: w1 = 0
        float hi = fmaxf(p0, p1);
        if (__all(hi <= m + 8.f)) {        // defer-max common path
            float w0 = __expf(p0 - m), w1 = __expf(p1 - m);
            l += w0 + w1;
            f32x2 w0v = {w0, w0}, w1v = {w1, w1};
            #pragma unroll
            for (int i = 0; i < P2; i++)
                accv[i] = __builtin_elementwise_fma(w0v, xl0v[i],
                          __builtin_elementwise_fma(w1v, xl1v[i], accv[i]));
        } else {                           // rescale path (first iter + rare)
            float mn = fmaxf(m, hi);
            float sc = __expf(m - mn);
            float w0 = __expf(p0 - mn), w1 = __expf(p1 - mn);
            l = fmaf(l, sc, w0 + w1);
            f32x2 scv = {sc, sc}, w0v = {w0, w0}, w1v = {w1, w1};
            #pragma unroll
            for (int i = 0; i < P2; i++)
                accv[i] = __builtin_elementwise_fma(accv[i], scv,
                          __builtin_elementwise_fma(w0v, xl0v[i], w1v * xl1v[i]));
            m = mn;
        }
        mdA = mdA_n; mdB = mdB_n; rA = rA_n; rB = rB_n;
    }

    float inv = 1.f / (l + 1e-16f);
    f32x2 invv = {inv, inv};
    f32x2 ov[P2];
    float s = 0.f, s2 = 0.f;
    #pragma unroll
    for (int i = 0; i < P2; i++) {
        f32x2 bov = *reinterpret_cast<const f32x2*>(&bo[cb + 2 * i]);
        ov[i] = __builtin_elementwise_fma(accv[i], invv, bov);
        s += ov[i].x + ov[i].y;
        s2 += ov[i].x * ov[i].x + ov[i].y * ov[i].y;
    }
    if constexpr (F32OUT) {
        float* q = outf + (size_t)n * HC + cb;
        if constexpr (CPL == 8) {
            *reinterpret_cast<float4*>(q)     = make_float4(ov[0].x, ov[0].y, ov[1].x, ov[1].y);
            *reinterpret_cast<float4*>(q + 4) = make_float4(ov[2].x, ov[2].y, ov[3].x, ov[3].y);
        } else if constexpr (CPL == 4) {
            *reinterpret_cast<float4*>(q) = make_float4(ov[0].x, ov[0].y, ov[1].x, ov[1].y);
        } else {
            *reinterpret_cast<float2*>(q) = make_float2(ov[0].x, ov[0].y);
        }
    } else {
        u16* q = outb + (size_t)n * HC + cb;
        if constexpr (CPL == 8) {
            *reinterpret_cast<uint4*>(q) =
                make_uint4(pack2(ov[0].x, ov[0].y), pack2(ov[1].x, ov[1].y),
                           pack2(ov[2].x, ov[2].y), pack2(ov[3].x, ov[3].y));
        } else if constexpr (CPL == 4) {
            *reinterpret_cast<uint2*>(q) =
                make_uint2(pack2(ov[0].x, ov[0].y), pack2(ov[1].x, ov[1].y));
        } else {
            *reinterpret_cast<unsigned*>(q) = pack2(ov[0].x, ov[0].y);
        }
    }
    #pragma unroll
    for (int off = 32; off; off >>= 1) {
        s += __shfl_xor(s, off);
        s2 += __shfl_xor(s2, off);
    }
    if (lane == 0) {
        double* bk = sbuck + (size_t)(blockIdx.x & 511) * 2;
        atomicAdd(bk, (double)s);
        atomicAdd(bk + 1, (double)s2);
    }
}

// ---------------------------------------------------------------- pooling: fused LN finalize + LN+ELU + goff search

__global__ __launch_bounds__(256) void pool_ln(const float* __restrict__ h,
                                               const int* __restrict__ batch,
                                               const double* __restrict__ buck,
                                               double count,
                                               const float* __restrict__ lw,
                                               const float* __restrict__ lb,
                                               float* __restrict__ out, int N) {
    float2 lp = reduce_buckets(buck, count);
    __shared__ float sh[128], mh[128];
    int g = blockIdx.x;
    int s_ = 0, hi_ = N;
    while (s_ < hi_) { int mid = (s_ + hi_) >> 1; if (batch[mid] < g) s_ = mid + 1; else hi_ = mid; }
    int e_ = s_, hi2 = N;
    while (e_ < hi2) { int mid = (e_ + hi2) >> 1; if (batch[mid] < g + 1) e_ = mid + 1; else hi2 = mid; }
    int tid = threadIdx.x;
    int c = tid & 127, part = tid >> 7;
    float wc = lw[c] * lp.y, bc = lb[c];
    float sum = 0.f, mx = -INFINITY;
    for (int n = s_ + part; n < e_; n += 2) {
        float v = elu_fast((h[(size_t)n * 128 + c] - lp.x) * wc + bc);
        sum += v;
        mx = fmaxf(mx, v);
    }
    if (part == 1) { sh[c] = sum; mh[c] = mx; }
    __syncthreads();
    if (part == 0) {
        if (e_ - s_ > 1) { sum += sh[c]; mx = fmaxf(mx, mh[c]); }
        int cnt = e_ - s_;
        out[g * 256 + c] = cnt > 0 ? sum / (float)cnt : 0.f;
        out[g * 256 + 128 + c] = cnt > 0 ? mx : 0.f;
    }
}

// ---------------------------------------------------------------- launch

extern "C" void kernel_launch(void* const* d_in, const int* in_sizes, int n_in,
                              void* d_out, int out_size, void* d_ws, size_t ws_size,
                              hipStream_t stream) {
    const int N = N_NODES, E = N_EDGES, G = N_GRAPHS, E2 = E2_TOTAL;
    const float* x = (const float*)d_in[0];
    const int* ei = (const int*)d_in[1];
    const float* eattr = (const float*)d_in[2];
    const int* batch = (const int*)d_in[3];
    auto P = [&](int l, int k) { return (const float*)d_in[4 + l * 9 + k]; };
    // k: 0=Wl 1=bl 2=Wr 3=br 4=We 5=att 6=bo 7=lnw 8=lnb

    char* w = (char*)d_ws;
    size_t off = 0;
    auto alloc = [&](size_t bytes) -> void* {
        void* p = w + off;
        off += (bytes + 255) & ~(size_t)255;
        return p;
    };
    u16* Xa = (u16*)alloc((size_t)N * 512 * 2);      // XL per layer
    u16* Xb = (u16*)alloc((size_t)N * 512 * 2);      // XR per layer
    u16* Xc = (u16*)alloc((size_t)N * 512 * 2);      // raw attn out per layer
    float* H3f = (float*)alloc((size_t)N * 128 * 4); // layer-3 attn out fp32
    float4* meta = (float4*)alloc((size_t)E2 * 16);  // CSR-ordered {ea, src}
    u16* WtL = (u16*)alloc((size_t)512 * 256 * 2);
    u16* WtR = (u16*)alloc((size_t)512 * 256 * 2);
    int* rowptr = (int*)alloc((size_t)(N + 1) * 4);
    int* cursor = (int*)alloc((size_t)N * 4);
    // zero-initialized region: [zs, ze)
    size_t zs = off;
    int* deg = (int*)alloc((size_t)N * 4);
    double* b1 = (double*)alloc(512 * 2 * 8);
    double* b2 = (double*)alloc(512 * 2 * 8);
    double* b3 = (double*)alloc(512 * 2 * 8);
    size_t ze = off;
    (void)ws_size; (void)n_in; (void)in_sizes; (void)out_size;

    hipMemsetAsync(w + zs, 0, ze - zs, stream);

    // prep: xw8 (Xa,Xb) + deg histogram in one dispatch
    prep_kernel<<<NBX + NBD, 256, 0, stream>>>(x, P(0, 0), P(0, 1), P(0, 2), P(0, 3),
                                               Xa, Xb, ei, deg, N, E);
    scan_kernel<<<1, 1024, 0, stream>>>(deg, rowptr, cursor, N);
    fill_kernel<<<(E + 255) / 256, 256, 0, stream>>>(ei, eattr, cursor, meta, E);
    loopfill_kernel<<<(N + 3) / 4, 256, 0, stream>>>(rowptr, meta, N);

    // -------- layer 1 (din=8, H=4, HC=512): SPLIT=2 (TLP probe)
    attn_wave<512, 2, false><<<(N * 2 + 3) / 4, 256, 0, stream>>>(
        rowptr, meta, Xa, Xb, P(0, 4), P(0, 5), P(0, 6), nullptr, Xc, b1, N);

    // -------- layer 2 (din=512, H=2, HC=256); LN+ELU fused into gemm A-path
    {
        dim3 tg(512 / 64, 256 / 64, 2);
        wt_dual<<<tg, 256, 0, stream>>>(P(1, 0), P(1, 2), WtL, WtR, 512, 256);
        dim3 gg((N + 127) / 128, 2);
        gemm_LR<<<gg, 256, 0, stream>>>(Xc, WtL, WtR, P(1, 1), P(1, 3),
                                        Xa, Xb, b1, (double)N * 512.0,
                                        P(0, 7), P(0, 8), N, 512, 256);
    }
    attn_wave<256, 2, false><<<(N * 2 + 3) / 4, 256, 0, stream>>>(
        rowptr, meta, Xa, Xb, P(1, 4), P(1, 5), P(1, 6), nullptr, Xc, b2, N);

    // -------- layer 3 (din=256, H=1, HC=128); LN+ELU fused into gemm A-path
    {
        dim3 tg(256 / 64, 128 / 64, 2);
        wt_dual<<<tg, 256, 0, stream>>>(P(2, 0), P(2, 2), WtL, WtR, 256, 128);
        dim3 gg((N + 127) / 128, 1);
        gemm_LR<<<gg, 256, 0, stream>>>(Xc, WtL, WtR, P(2, 1), P(2, 3),
                                        Xa, Xb, b2, (double)N * 256.0,
                                        P(1, 7), P(1, 8), N, 256, 128);
    }
    attn_wave<128, 1, true><<<(N + 3) / 4, 256, 0, stream>>>(
        rowptr, meta, Xa, Xb, P(2, 4), P(2, 5), P(2, 6), H3f, nullptr, b3, N);

    // -------- pooling (fused LN finalize + apply + goff search)
    pool_ln<<<G, 256, 0, stream>>>(H3f, batch, b3, (double)N * 128.0,
                                   P(2, 7), P(2, 8), (float*)d_out, N);
}

// Round 17
// 765.274 us; speedup vs baseline: 1.0821x; 1.0821x over previous
//
#include <hip/hip_runtime.h>
#include <hip/hip_bf16.h>
#include <math.h>

#define N_NODES 50000
#define N_EDGES 800000
#define N_GRAPHS 64
#define E2_TOTAL (N_EDGES + N_NODES)
#define NBX ((N_NODES + 63) / 64)       // xw8 blocks
#define NBD ((N_EDGES + 255) / 256)     // deg blocks

typedef unsigned short u16;
typedef __attribute__((ext_vector_type(8))) short s16x8;
typedef __attribute__((ext_vector_type(4))) float f32x4;
typedef __attribute__((ext_vector_type(2))) float f32x2;

__device__ __forceinline__ u16 f2bf(float f) {
    unsigned u = __float_as_uint(f);
    u += 0x7fffu + ((u >> 16) & 1u);   // round-to-nearest-even
    return (u16)(u >> 16);
}
__device__ __forceinline__ void unpack2(unsigned v, float& a, float& b) {
    a = __uint_as_float(v << 16);
    b = __uint_as_float(v & 0xffff0000u);
}
__device__ __forceinline__ f32x2 up2(unsigned v) {
    f32x2 r;
    r.x = __uint_as_float(v << 16);
    r.y = __uint_as_float(v & 0xffff0000u);
    return r;
}
__device__ __forceinline__ unsigned pack2(float a, float b) {
    return (unsigned)f2bf(a) | ((unsigned)f2bf(b) << 16);
}
__device__ __forceinline__ float elu_fast(float u) {
    return u > 0.f ? u : __expf(u) - 1.f;
}

// ---------------------------------------------------------------- prep: xw8 (blocks [0,NBX)) + deg histogram (blocks [NBX, NBX+NBD))

__global__ __launch_bounds__(256) void prep_kernel(
    const float* __restrict__ x, const float* __restrict__ Wl,
    const float* __restrict__ bl, const float* __restrict__ Wr,
    const float* __restrict__ br, u16* __restrict__ Xa, u16* __restrict__ Xb,
    const int* __restrict__ ei, int* __restrict__ deg, int N, int E) {
    int tid = threadIdx.x;
    if (blockIdx.x >= NBX) {
        int e = (blockIdx.x - NBX) * 256 + tid;
        if (e < E) atomicAdd(&deg[ei[E + e]], 1);
        return;
    }
    __shared__ float sWl[8 * 512], sWr[8 * 512];
    __shared__ float sbl[512], sbr[512];
    __shared__ float sx[64][8];
    int nb = blockIdx.x * 64;
    for (int i = tid; i < 8 * 512; i += 256) { sWl[i] = Wl[i]; sWr[i] = Wr[i]; }
    for (int i = tid; i < 512; i += 256) { sbl[i] = bl[i]; sbr[i] = br[i]; }
    for (int i = tid; i < 64 * 8; i += 256) {
        int j = i >> 3, k = i & 7;
        int n = nb + j;
        sx[j][k] = (n < N) ? x[(size_t)n * 8 + k] : 0.f;
    }
    __syncthreads();
    for (int it = 0; it < 64; it++) {
        int i = tid + it * 256;
        int j = i >> 8, c2 = (i & 255) * 2;
        int n = nb + j;
        if (n < N) {
            float l0 = sbl[c2], l1 = sbl[c2 + 1];
            float r0 = sbr[c2], r1 = sbr[c2 + 1];
            #pragma unroll
            for (int k = 0; k < 8; k++) {
                float xv = sx[j][k];
                l0 += xv * sWl[k * 512 + c2];
                l1 += xv * sWl[k * 512 + c2 + 1];
                r0 += xv * sWr[k * 512 + c2];
                r1 += xv * sWr[k * 512 + c2 + 1];
            }
            *reinterpret_cast<unsigned*>(Xa + (size_t)n * 512 + c2) = pack2(l0, l1);
            *reinterpret_cast<unsigned*>(Xb + (size_t)n * 512 + c2) = pack2(r0, r1);
        }
    }
}

// exclusive scan of (deg+1); writes rowptr AND cursor
__global__ __launch_bounds__(1024) void scan_kernel(const int* __restrict__ deg,
                                                    int* __restrict__ rowptr,
                                                    int* __restrict__ cursor, int N) {
    __shared__ int wsum[16];
    __shared__ int carry_s;
    int tid = threadIdx.x, lane = tid & 63, wid = tid >> 6;
    if (tid == 0) carry_s = 0;
    __syncthreads();
    for (int base = 0; base < N; base += 4096) {
        int i0 = base + tid * 4;
        int d0 = (i0 + 0 < N) ? deg[i0 + 0] + 1 : 0;
        int d1 = (i0 + 1 < N) ? deg[i0 + 1] + 1 : 0;
        int d2 = (i0 + 2 < N) ? deg[i0 + 2] + 1 : 0;
        int d3 = (i0 + 3 < N) ? deg[i0 + 3] + 1 : 0;
        int v = d0 + d1 + d2 + d3;
        int x = v;
        #pragma unroll
        for (int off = 1; off < 64; off <<= 1) {
            int t = __shfl_up(x, off);
            if (lane >= off) x += t;
        }
        if (lane == 63) wsum[wid] = x;
        __syncthreads();
        if (wid == 0) {
            int y = (lane < 16) ? wsum[lane] : 0;
            #pragma unroll
            for (int off = 1; off < 16; off <<= 1) {
                int t = __shfl_up(y, off);
                if (lane >= off) y += t;
            }
            if (lane < 16) wsum[lane] = y;
        }
        __syncthreads();
        int woff = (wid > 0) ? wsum[wid - 1] : 0;
        int excl = carry_s + woff + x - v;
        if (i0 + 0 < N) { rowptr[i0 + 0] = excl;                cursor[i0 + 0] = excl; }
        if (i0 + 1 < N) { rowptr[i0 + 1] = excl + d0;           cursor[i0 + 1] = excl + d0; }
        if (i0 + 2 < N) { rowptr[i0 + 2] = excl + d0 + d1;      cursor[i0 + 2] = excl + d0 + d1; }
        if (i0 + 3 < N) { rowptr[i0 + 3] = excl + d0 + d1 + d2; cursor[i0 + 3] = excl + d0 + d1 + d2; }
        __syncthreads();
        if (tid == 1023) carry_s += wsum[15];
        __syncthreads();
    }
    if (threadIdx.x == 0) rowptr[N] = carry_s;
}

// CSR fill (real edges only): meta[pos] = {ea0, ea1, ea2, src}
__global__ __launch_bounds__(256) void fill_kernel(const int* __restrict__ ei,
                                                   const float* __restrict__ eattr,
                                                   int* __restrict__ cursor,
                                                   float4* __restrict__ meta, int E) {
    int e = blockIdx.x * 256 + threadIdx.x;
    if (e >= E) return;
    int src = ei[e], dst = ei[E + e];
    float a0 = eattr[(size_t)e * 3 + 0];
    float a1 = eattr[(size_t)e * 3 + 1];
    float a2 = eattr[(size_t)e * 3 + 2];
    int pos = atomicAdd(&cursor[dst], 1);
    meta[pos] = make_float4(a0, a1, a2, __int_as_float(src));
}

// self-loop fill: one wave per node reduces its real-edge attrs, writes the
// self-loop entry into the LAST slot of the node's CSR range.
__global__ __launch_bounds__(256) void loopfill_kernel(const int* __restrict__ rowptr,
                                                       float4* __restrict__ meta, int N) {
    int n = blockIdx.x * 4 + (threadIdx.x >> 6);
    int lane = threadIdx.x & 63;
    if (n >= N) return;
    int beg = __builtin_amdgcn_readfirstlane(rowptr[n]);
    int e1  = __builtin_amdgcn_readfirstlane(rowptr[n + 1]) - 1;  // self-loop slot
    float a0 = 0.f, a1 = 0.f, a2 = 0.f;
    for (int j = beg + lane; j < e1; j += 64) {
        float4 md = meta[j];
        a0 += md.x; a1 += md.y; a2 += md.z;
    }
    #pragma unroll
    for (int off = 32; off; off >>= 1) {
        a0 += __shfl_xor(a0, off);
        a1 += __shfl_xor(a1, off);
        a2 += __shfl_xor(a2, off);
    }
    if (lane == 0) {
        int cnt = e1 - beg;
        float inv = 1.f / (float)max(cnt, 1);
        meta[e1] = make_float4(a0 * inv, a1 * inv, a2 * inv, __int_as_float(n));
    }
}

// ---------------------------------------------------------------- bucket reduce helper (in-block, 256 thr)

__device__ __forceinline__ float2 reduce_buckets(const double* __restrict__ buck,
                                                 double count) {
    __shared__ float2 res;
    int t = threadIdx.x;
    double s  = buck[t * 2]     + buck[(t + 256) * 2];
    double s2 = buck[t * 2 + 1] + buck[(t + 256) * 2 + 1];
    #pragma unroll
    for (int off = 32; off; off >>= 1) {
        s += __shfl_xor(s, off);
        s2 += __shfl_xor(s2, off);
    }
    __shared__ double a[4], b[4];
    int wid = t >> 6, lane = t & 63;
    if (lane == 0) { a[wid] = s; b[wid] = s2; }
    __syncthreads();
    if (t == 0) {
        double S = a[0] + a[1] + a[2] + a[3];
        double S2 = b[0] + b[1] + b[2] + b[3];
        double mu = S / count;
        double var = S2 / count - mu * mu;
        float sd = (float)sqrt(var > 0.0 ? var : 0.0);
        res.x = (float)mu;
        res.y = 1.f / (sd + 1e-5f);
    }
    __syncthreads();
    return res;
}

// ---------------------------------------------------------------- W -> Wt bf16 transpose (dual via blockIdx.z)

__global__ __launch_bounds__(256) void wt_dual(const float* __restrict__ WL,
                                               const float* __restrict__ WR,
                                               u16* __restrict__ WtL,
                                               u16* __restrict__ WtR, int K, int M) {
    const float* W = blockIdx.z ? WR : WL;
    u16* Wt = blockIdx.z ? WtR : WtL;
    __shared__ u16 t[64][65];
    int kb = blockIdx.x * 64, mb = blockIdx.y * 64;
    int tid = threadIdx.x;
    for (int i = tid; i < 64 * 64; i += 256) {
        int k = i >> 6, m = i & 63;
        t[m][k] = f2bf(W[(size_t)(kb + k) * M + mb + m]);
    }
    __syncthreads();
    for (int i = tid; i < 64 * 64; i += 256) {
        int m = i >> 6, k = i & 63;
        Wt[(size_t)(mb + m) * K + kb + k] = t[m][k];
    }
}

// ---------------------------------------------------------------- MFMA GEMM, L and R fused in one pass
// A-tile staged ONCE with fused LayerNorm + fast-ELU, used against both BtL
// and BtR (af fragments reused). XOR-swizzled LDS (write and read).

__global__ __launch_bounds__(256) void gemm_LR(const u16* __restrict__ A,
                                               const u16* __restrict__ BtL,
                                               const u16* __restrict__ BtR,
                                               const float* __restrict__ biasL,
                                               const float* __restrict__ biasR,
                                               u16* __restrict__ YL,
                                               u16* __restrict__ YR,
                                               const double* __restrict__ buck,
                                               double count,
                                               const float* __restrict__ lnw,
                                               const float* __restrict__ lnb,
                                               int N, int K, int M) {
    constexpr int BM = 128, BK = 64;
    __shared__ u16 As[BM][BK];
    __shared__ u16 BsL[BM][BK];
    __shared__ u16 BsR[BM][BK];
    __shared__ float sLw[512], sLb[512];
    float2 lp = reduce_buckets(buck, count);
    float muf = lp.x, rs = lp.y;
    int tid = threadIdx.x;
    for (int i = tid; i < K; i += 256) { sLw[i] = lnw[i] * rs; sLb[i] = lnb[i]; }
    int wid = tid >> 6, lane = tid & 63;
    int wm = (wid >> 1) * 64, wn = (wid & 1) * 64;
    int bm = blockIdx.x * BM, bn = blockIdx.y * BM;
    int l15 = lane & 15, l4 = lane >> 4;
    f32x4 accL[4][4] = {};
    f32x4 accR[4][4] = {};
    int sr = tid >> 3;            // 0..31
    int cbw = tid & 7;            // col-block 0..7
    int sc = cbw * 8;
    __syncthreads();

    for (int k0 = 0; k0 < K; k0 += BK) {
        #pragma unroll
        for (int p = 0; p < 4; p++) {
            int r = p * 32 + sr;
            int swc = ((cbw ^ (r & 7)) * 8);
            int grow = bm + r;
            uint4 av = make_uint4(0, 0, 0, 0);
            if (grow < N) {
                av = *reinterpret_cast<const uint4*>(A + (size_t)grow * K + k0 + sc);
                float f[8];
                unpack2(av.x, f[0], f[1]); unpack2(av.y, f[2], f[3]);
                unpack2(av.z, f[4], f[5]); unpack2(av.w, f[6], f[7]);
                #pragma unroll
                for (int q = 0; q < 8; q++) {
                    int c = k0 + sc + q;
                    f[q] = elu_fast((f[q] - muf) * sLw[c] + sLb[c]);
                }
                av = make_uint4(pack2(f[0], f[1]), pack2(f[2], f[3]),
                                pack2(f[4], f[5]), pack2(f[6], f[7]));
            }
            *reinterpret_cast<uint4*>(&As[r][swc]) = av;
            *reinterpret_cast<uint4*>(&BsL[r][swc]) =
                *reinterpret_cast<const uint4*>(BtL + (size_t)(bn + r) * K + k0 + sc);
            *reinterpret_cast<uint4*>(&BsR[r][swc]) =
                *reinterpret_cast<const uint4*>(BtR + (size_t)(bn + r) * K + k0 + sc);
        }
        __syncthreads();
        #pragma unroll
        for (int kk = 0; kk < 2; kk++) {
            int CB = kk * 4 + l4;     // col-block 0..7
            s16x8 af[4], bfL[4], bfR[4];
            #pragma unroll
            for (int i = 0; i < 4; i++) {
                int Ra = wm + i * 16 + l15;
                int Rb = wn + i * 16 + l15;
                int sa = (CB ^ (Ra & 7)) * 8;
                int sb = (CB ^ (Rb & 7)) * 8;
                af[i]  = *reinterpret_cast<const s16x8*>(&As[Ra][sa]);
                bfL[i] = *reinterpret_cast<const s16x8*>(&BsL[Rb][sb]);
                bfR[i] = *reinterpret_cast<const s16x8*>(&BsR[Rb][sb]);
            }
            #pragma unroll
            for (int i = 0; i < 4; i++)
                #pragma unroll
                for (int j = 0; j < 4; j++) {
                    accL[i][j] = __builtin_amdgcn_mfma_f32_16x16x32_bf16(
                        af[i], bfL[j], accL[i][j], 0, 0, 0);
                    accR[i][j] = __builtin_amdgcn_mfma_f32_16x16x32_bf16(
                        af[i], bfR[j], accR[i][j], 0, 0, 0);
                }
        }
        __syncthreads();
    }
    #pragma unroll
    for (int i = 0; i < 4; i++) {
        #pragma unroll
        for (int j = 0; j < 4; j++) {
            int col = bn + wn + j * 16 + l15;
            float bvL = biasL[col];
            float bvR = biasR[col];
            #pragma unroll
            for (int r = 0; r < 4; r++) {
                int row = bm + wm + i * 16 + l4 * 4 + r;
                if (row < N) {
                    YL[(size_t)row * M + col] = f2bf(accL[i][j][r] + bvL);
                    YR[(size_t)row * M + col] = f2bf(accR[i][j][r] + bvR);
                }
            }
        }
    }
}

// ---------------------------------------------------------------- wave-per-node GATv2
// One wave per node. Scalar (SGPR) row bases, packed-f32 channel math,
// 2 edges/iter with 2-ahead prefetch, defer-max softmax, LN-stat buckets.

template <int HC, int SPLIT, bool F32OUT>
__global__ __launch_bounds__(256) void attn_wave(
    const int* __restrict__ rowptr, const float4* __restrict__ meta,
    const u16* __restrict__ XLbf, const u16* __restrict__ XRbf,
    const float* __restrict__ We, const float* __restrict__ att,
    const float* __restrict__ bo, float* __restrict__ outf,
    u16* __restrict__ outb, double* __restrict__ sbuck, int N) {
    constexpr int CW  = HC / SPLIT;   // channels per wave
    constexpr int CPL = CW / 64;      // 8, 4 or 2
    constexpr int P2  = CPL / 2;      // float2 pairs per lane
    constexpr int GS  = 128 / CPL;    // lanes per head group (16/32/64)
    constexpr int SHB = (HC == 512) ? 10 : (HC == 256) ? 9 : 8;  // log2(row bytes)
    int gw = blockIdx.x * 4 + (threadIdx.x >> 6);
    int lane = threadIdx.x & 63;
    int n = gw / SPLIT;
    int sub = gw - n * SPLIT;
    if (n >= N) return;
    int cb = sub * CW + lane * CPL;

    f32x2 xr2[P2], we0v[P2], we1v[P2], we2v[P2], sav[P2], accv[P2];
    #pragma unroll
    for (int i = 0; i < P2; i++) {
        we0v[i] = *reinterpret_cast<const f32x2*>(&We[cb + 2 * i]);
        we1v[i] = *reinterpret_cast<const f32x2*>(&We[HC + cb + 2 * i]);
        we2v[i] = *reinterpret_cast<const f32x2*>(&We[2 * HC + cb + 2 * i]);
        sav[i]  = *reinterpret_cast<const f32x2*>(&att[cb + 2 * i]);
        accv[i] = f32x2{0.f, 0.f};
    }
    auto ldrow = [&](const u16* base, int idx) -> uint4 {
        const u16* p = (const u16*)((const char*)base +
                       ((size_t)((unsigned)idx << SHB))) + cb;
        if constexpr (CPL == 8) {
            return *reinterpret_cast<const uint4*>(p);
        } else if constexpr (CPL == 4) {
            uint2 r = *reinterpret_cast<const uint2*>(p);
            return make_uint4(r.x, r.y, 0, 0);
        } else {
            return make_uint4(*reinterpret_cast<const unsigned*>(p), 0, 0, 0);
        }
    };
    auto toF2 = [&](uint4 r, f32x2* v) {
        v[0] = up2(r.x);
        if constexpr (CPL >= 4) v[1] = up2(r.y);
        if constexpr (CPL == 8) { v[2] = up2(r.z); v[3] = up2(r.w); }
    };
    {
        uint4 r = ldrow(XRbf, n);
        toF2(r, xr2);
    }

    int beg = __builtin_amdgcn_readfirstlane(rowptr[n]);
    int end = __builtin_amdgcn_readfirstlane(rowptr[n + 1]);
    int e1 = end - 1;
    float m = -INFINITY, l = 0.f;

    float4 mdA = meta[beg];
    float4 mdB = meta[min(beg + 1, e1)];
    int sA = __builtin_amdgcn_readfirstlane(__float_as_int(mdA.w));
    int sB = __builtin_amdgcn_readfirstlane(__float_as_int(mdB.w));
    uint4 rA = ldrow(XLbf, sA), rB = ldrow(XLbf, sB);

    for (int j = beg; j < end; j += 2) {
        float4 mdA_n = meta[min(j + 2, e1)];
        float4 mdB_n = meta[min(j + 3, e1)];
        int sAn = __builtin_amdgcn_readfirstlane(__float_as_int(mdA_n.w));
        int sBn = __builtin_amdgcn_readfirstlane(__float_as_int(mdB_n.w));
        uint4 rA_n = ldrow(XLbf, sAn), rB_n = ldrow(XLbf, sBn);

        f32x2 xl0v[P2], xl1v[P2];
        toF2(rA, xl0v);
        toF2(rB, xl1v);
        f32x2 pv0 = {0.f, 0.f}, pv1 = {0.f, 0.f};
        f32x2 ax0 = {mdA.x, mdA.x}, ay0 = {mdA.y, mdA.y}, az0 = {mdA.z, mdA.z};
        f32x2 ax1 = {mdB.x, mdB.x}, ay1 = {mdB.y, mdB.y}, az1 = {mdB.z, mdB.z};
        #pragma unroll
        for (int i = 0; i < P2; i++) {
            f32x2 u0 = __builtin_elementwise_fma(ax0, we0v[i],
                       __builtin_elementwise_fma(ay0, we1v[i],
                       __builtin_elementwise_fma(az0, we2v[i], xl0v[i] + xr2[i])));
            f32x2 u1 = __builtin_elementwise_fma(ax1, we0v[i],
                       __builtin_elementwise_fma(ay1, we1v[i],
                       __builtin_elementwise_fma(az1, we2v[i], xl1v[i] + xr2[i])));
            f32x2 lr0 = __builtin_elementwise_max(u0, u0 * 0.2f);
            f32x2 lr1 = __builtin_elementwise_max(u1, u1 * 0.2f);
            pv0 = __builtin_elementwise_fma(lr0, sav[i], pv0);
            pv1 = __builtin_elementwise_fma(lr1, sav[i], pv1);
        }
        float p0 = pv0.x + pv0.y;
        float p1 = pv1.x + pv1.y;
        #pragma unroll
        for (int off = GS / 2; off >= 1; off >>= 1) {
            p0 += __shfl_xor(p0, off);
            p1 += __shfl_xor(p1, off);
        }
        if (j + 1 > e1) p1 = -INFINITY;   // odd tail: w1 = 0
        float hi = fmaxf(p0, p1);
        if (__all(hi <= m + 8.f)) {        // defer-max common path
            float w0 = __expf(p0 - m), w1 = __expf(p1 - m);
            l += w0 + w1;
            f32x2 w0v = {w0, w0}, w1v = {w1, w1};
            #pragma unroll
            for (int i = 0; i < P2; i++)
                accv[i] = __builtin_elementwise_fma(w0v, xl0v[i],
                          __builtin_elementwise_fma(w1v, xl1v[i], accv[i]));
        } else {                           // rescale path (first iter + rare)
            float mn = fmaxf(m, hi);
            float sc = __expf(m - mn);
            float w0 = __expf(p0 - mn), w1 = __expf(p1 - mn);
            l = fmaf(l, sc, w0 + w1);
            f32x2 scv = {sc, sc}, w0v = {w0, w0}, w1v = {w1, w1};
            #pragma unroll
            for (int i = 0; i < P2; i++)
                accv[i] = __builtin_elementwise_fma(accv[i], scv,
                          __builtin_elementwise_fma(w0v, xl0v[i], w1v * xl1v[i]));
            m = mn;
        }
        mdA = mdA_n; mdB = mdB_n; rA = rA_n; rB = rB_n;
    }

    float inv = 1.f / (l + 1e-16f);
    f32x2 invv = {inv, inv};
    f32x2 ov[P2];
    float s = 0.f, s2 = 0.f;
    #pragma unroll
    for (int i = 0; i < P2; i++) {
        f32x2 bov = *reinterpret_cast<const f32x2*>(&bo[cb + 2 * i]);
        ov[i] = __builtin_elementwise_fma(accv[i], invv, bov);
        s += ov[i].x + ov[i].y;
        s2 += ov[i].x * ov[i].x + ov[i].y * ov[i].y;
    }
    if constexpr (F32OUT) {
        float* q = outf + (size_t)n * HC + cb;
        if constexpr (CPL == 8) {
            *reinterpret_cast<float4*>(q)     = make_float4(ov[0].x, ov[0].y, ov[1].x, ov[1].y);
            *reinterpret_cast<float4*>(q + 4) = make_float4(ov[2].x, ov[2].y, ov[3].x, ov[3].y);
        } else if constexpr (CPL == 4) {
            *reinterpret_cast<float4*>(q) = make_float4(ov[0].x, ov[0].y, ov[1].x, ov[1].y);
        } else {
            *reinterpret_cast<float2*>(q) = make_float2(ov[0].x, ov[0].y);
        }
    } else {
        u16* q = outb + (size_t)n * HC + cb;
        if constexpr (CPL == 8) {
            *reinterpret_cast<uint4*>(q) =
                make_uint4(pack2(ov[0].x, ov[0].y), pack2(ov[1].x, ov[1].y),
                           pack2(ov[2].x, ov[2].y), pack2(ov[3].x, ov[3].y));
        } else if constexpr (CPL == 4) {
            *reinterpret_cast<uint2*>(q) =
                make_uint2(pack2(ov[0].x, ov[0].y), pack2(ov[1].x, ov[1].y));
        } else {
            *reinterpret_cast<unsigned*>(q) = pack2(ov[0].x, ov[0].y);
        }
    }
    #pragma unroll
    for (int off = 32; off; off >>= 1) {
        s += __shfl_xor(s, off);
        s2 += __shfl_xor(s2, off);
    }
    if (lane == 0) {
        double* bk = sbuck + (size_t)(blockIdx.x & 511) * 2;
        atomicAdd(bk, (double)s);
        atomicAdd(bk + 1, (double)s2);
    }
}

// ---------------------------------------------------------------- pooling: fused LN finalize + LN+ELU + goff search

__global__ __launch_bounds__(256) void pool_ln(const float* __restrict__ h,
                                               const int* __restrict__ batch,
                                               const double* __restrict__ buck,
                                               double count,
                                               const float* __restrict__ lw,
                                               const float* __restrict__ lb,
                                               float* __restrict__ out, int N) {
    float2 lp = reduce_buckets(buck, count);
    __shared__ float sh[128], mh[128];
    int g = blockIdx.x;
    int s_ = 0, hi_ = N;
    while (s_ < hi_) { int mid = (s_ + hi_) >> 1; if (batch[mid] < g) s_ = mid + 1; else hi_ = mid; }
    int e_ = s_, hi2 = N;
    while (e_ < hi2) { int mid = (e_ + hi2) >> 1; if (batch[mid] < g + 1) e_ = mid + 1; else hi2 = mid; }
    int tid = threadIdx.x;
    int c = tid & 127, part = tid >> 7;
    float wc = lw[c] * lp.y, bc = lb[c];
    float sum = 0.f, mx = -INFINITY;
    for (int n = s_ + part; n < e_; n += 2) {
        float v = elu_fast((h[(size_t)n * 128 + c] - lp.x) * wc + bc);
        sum += v;
        mx = fmaxf(mx, v);
    }
    if (part == 1) { sh[c] = sum; mh[c] = mx; }
    __syncthreads();
    if (part == 0) {
        if (e_ - s_ > 1) { sum += sh[c]; mx = fmaxf(mx, mh[c]); }
        int cnt = e_ - s_;
        out[g * 256 + c] = cnt > 0 ? sum / (float)cnt : 0.f;
        out[g * 256 + 128 + c] = cnt > 0 ? mx : 0.f;
    }
}

// ---------------------------------------------------------------- launch

extern "C" void kernel_launch(void* const* d_in, const int* in_sizes, int n_in,
                              void* d_out, int out_size, void* d_ws, size_t ws_size,
                              hipStream_t stream) {
    const int N = N_NODES, E = N_EDGES, G = N_GRAPHS, E2 = E2_TOTAL;
    const float* x = (const float*)d_in[0];
    const int* ei = (const int*)d_in[1];
    const float* eattr = (const float*)d_in[2];
    const int* batch = (const int*)d_in[3];
    auto P = [&](int l, int k) { return (const float*)d_in[4 + l * 9 + k]; };
    // k: 0=Wl 1=bl 2=Wr 3=br 4=We 5=att 6=bo 7=lnw 8=lnb

    char* w = (char*)d_ws;
    size_t off = 0;
    auto alloc = [&](size_t bytes) -> void* {
        void* p = w + off;
        off += (bytes + 255) & ~(size_t)255;
        return p;
    };
    u16* Xa = (u16*)alloc((size_t)N * 512 * 2);      // XL per layer
    u16* Xb = (u16*)alloc((size_t)N * 512 * 2);      // XR per layer
    u16* Xc = (u16*)alloc((size_t)N * 512 * 2);      // raw attn out per layer
    float* H3f = (float*)alloc((size_t)N * 128 * 4); // layer-3 attn out fp32
    float4* meta = (float4*)alloc((size_t)E2 * 16);  // CSR-ordered {ea, src}
    u16* WtL = (u16*)alloc((size_t)512 * 256 * 2);
    u16* WtR = (u16*)alloc((size_t)512 * 256 * 2);
    int* rowptr = (int*)alloc((size_t)(N + 1) * 4);
    int* cursor = (int*)alloc((size_t)N * 4);
    // zero-initialized region: [zs, ze)
    size_t zs = off;
    int* deg = (int*)alloc((size_t)N * 4);
    double* b1 = (double*)alloc(512 * 2 * 8);
    double* b2 = (double*)alloc(512 * 2 * 8);
    double* b3 = (double*)alloc(512 * 2 * 8);
    size_t ze = off;
    (void)ws_size; (void)n_in; (void)in_sizes; (void)out_size;

    hipMemsetAsync(w + zs, 0, ze - zs, stream);

    // prep: xw8 (Xa,Xb) + deg histogram in one dispatch
    prep_kernel<<<NBX + NBD, 256, 0, stream>>>(x, P(0, 0), P(0, 1), P(0, 2), P(0, 3),
                                               Xa, Xb, ei, deg, N, E);
    scan_kernel<<<1, 1024, 0, stream>>>(deg, rowptr, cursor, N);
    fill_kernel<<<(E + 255) / 256, 256, 0, stream>>>(ei, eattr, cursor, meta, E);
    loopfill_kernel<<<(N + 3) / 4, 256, 0, stream>>>(rowptr, meta, N);

    // -------- layer 1 (din=8, H=4, HC=512): SPLIT=1, CPL=8
    attn_wave<512, 1, false><<<(N + 3) / 4, 256, 0, stream>>>(
        rowptr, meta, Xa, Xb, P(0, 4), P(0, 5), P(0, 6), nullptr, Xc, b1, N);

    // -------- layer 2 (din=512, H=2, HC=256); LN+ELU fused into gemm A-path
    {
        dim3 tg(512 / 64, 256 / 64, 2);
        wt_dual<<<tg, 256, 0, stream>>>(P(1, 0), P(1, 2), WtL, WtR, 512, 256);
        dim3 gg((N + 127) / 128, 2);
        gemm_LR<<<gg, 256, 0, stream>>>(Xc, WtL, WtR, P(1, 1), P(1, 3),
                                        Xa, Xb, b1, (double)N * 512.0,
                                        P(0, 7), P(0, 8), N, 512, 256);
    }
    attn_wave<256, 1, false><<<(N + 3) / 4, 256, 0, stream>>>(
        rowptr, meta, Xa, Xb, P(1, 4), P(1, 5), P(1, 6), nullptr, Xc, b2, N);

    // -------- layer 3 (din=256, H=1, HC=128); LN+ELU fused into gemm A-path
    {
        dim3 tg(256 / 64, 128 / 64, 2);
        wt_dual<<<tg, 256, 0, stream>>>(P(2, 0), P(2, 2), WtL, WtR, 256, 128);
        dim3 gg((N + 127) / 128, 1);
        gemm_LR<<<gg, 256, 0, stream>>>(Xc, WtL, WtR, P(2, 1), P(2, 3),
                                        Xa, Xb, b2, (double)N * 256.0,
                                        P(1, 7), P(1, 8), N, 256, 128);
    }
    attn_wave<128, 1, true><<<(N + 3) / 4, 256, 0, stream>>>(
        rowptr, meta, Xa, Xb, P(2, 4), P(2, 5), P(2, 6), H3f, nullptr, b3, N);

    // -------- pooling (fused LN finalize + apply + goff search)
    pool_ln<<<G, 256, 0, stream>>>(H3f, batch, b3, (double)N * 128.0,
                                   P(2, 7), P(2, 8), (float*)d_out, N);
}